// Round 3
// baseline (2473.615 us; speedup 1.0000x reference)
//
#include <hip/hip_runtime.h>

// GCN, 2 layers, in-dim 1. Reduced to scalar-per-node propagation:
//   deg[c]  = 1 + indeg(c);  dinv = rsqrt(deg)
//   S[c]    = dinv[c] * ( dinv[c]*x[c] + sum_{(r,c) in E} dinv[r]*x[r] )
//   t[r]    = sum_f relu(b1[f] + W1[f]*S[r]) * W2[f]
//   y[c]    = clip( b2 + dinv[c] * ( dinv[c]*t[c] + sum_{(r,c)} dinv[r]*t[r] ), -0.5, 9.5 )
// NOTE: harness passes integer inputs as int32 (edge_index -> const int*).
// ws layout (floats): [0,N) deg->dinv | [N,2N) xd | [2N,3N) acc1->td
// d_out doubles as acc2 (zeroed here, scatter-added, finalized in place).

__global__ void gcn_init(float* __restrict__ deg, float* __restrict__ acc1,
                         float* __restrict__ acc2, int n) {
    int i = blockIdx.x * blockDim.x + threadIdx.x;
    if (i < n) { deg[i] = 1.0f; acc1[i] = 0.0f; acc2[i] = 0.0f; }
}

__global__ void gcn_deg(const int* __restrict__ col, float* __restrict__ deg, int e) {
    int i = blockIdx.x * blockDim.x + threadIdx.x;
    if (i < e) atomicAdd(&deg[col[i]], 1.0f);
}

__global__ void gcn_dinv(const float* __restrict__ x, float* __restrict__ deg_dinv,
                         float* __restrict__ xd, int n) {
    int i = blockIdx.x * blockDim.x + threadIdx.x;
    if (i < n) {
        float d = rsqrtf(deg_dinv[i]);
        deg_dinv[i] = d;
        xd[i] = d * x[i];
    }
}

__global__ void gcn_scatter(const int* __restrict__ row, const int* __restrict__ col,
                            const float* __restrict__ v, float* __restrict__ acc, int e) {
    int i = blockIdx.x * blockDim.x + threadIdx.x;
    if (i < e) atomicAdd(&acc[col[i]], v[row[i]]);
}

__global__ void gcn_mid(const float* __restrict__ dinv, const float* __restrict__ xd,
                        float* __restrict__ acc1_td,
                        const float* __restrict__ W1, const float* __restrict__ b1,
                        const float* __restrict__ W2, int n) {
    int i = blockIdx.x * blockDim.x + threadIdx.x;
    if (i < n) {
        float d = dinv[i];
        float S = d * (acc1_td[i] + xd[i]);   // scatter sum + self-loop term
        float t = 0.0f;
        #pragma unroll
        for (int f = 0; f < 10; ++f) {
            float h = fmaf(W1[f], S, b1[f]);
            h = h > 0.0f ? h : 0.0f;
            t = fmaf(h, W2[f], t);
        }
        acc1_td[i] = d * t;                   // td = dinv * t, reuse acc1 slot
    }
}

__global__ void gcn_final(const float* __restrict__ dinv, const float* __restrict__ td,
                          const float* __restrict__ b2,
                          float* __restrict__ out_acc2, int n) {
    int i = blockIdx.x * blockDim.x + threadIdx.x;
    if (i < n) {
        float y = b2[0] + dinv[i] * (out_acc2[i] + td[i]);  // scatter + self-loop
        y = fminf(fmaxf(y, -0.5f), 9.5f);
        out_acc2[i] = y;
    }
}

extern "C" void kernel_launch(void* const* d_in, const int* in_sizes, int n_in,
                              void* d_out, int out_size, void* d_ws, size_t ws_size,
                              hipStream_t stream) {
    const float* x  = (const float*)d_in[0];
    const int*   ei = (const int*)d_in[1];     // int32 per harness convention
    const float* W1 = (const float*)d_in[2];
    const float* b1 = (const float*)d_in[3];
    const float* W2 = (const float*)d_in[4];
    const float* b2 = (const float*)d_in[5];

    const int n = in_sizes[0];        // 500000
    const int e = in_sizes[1] / 2;    // 16000000
    const int* row = ei;
    const int* col = ei + e;

    float* deg_dinv = (float*)d_ws;
    float* xd       = deg_dinv + n;
    float* acc1     = deg_dinv + 2 * (size_t)n;
    float* out      = (float*)d_out;  // doubles as acc2

    const int B = 256;
    const int gn = (n + B - 1) / B;
    const int ge = (e + B - 1) / B;

    gcn_init   <<<gn, B, 0, stream>>>(deg_dinv, acc1, out, n);
    gcn_deg    <<<ge, B, 0, stream>>>(col, deg_dinv, e);
    gcn_dinv   <<<gn, B, 0, stream>>>(x, deg_dinv, xd, n);
    gcn_scatter<<<ge, B, 0, stream>>>(row, col, xd, acc1, e);
    gcn_mid    <<<gn, B, 0, stream>>>(deg_dinv, xd, acc1, W1, b1, W2, n);
    gcn_scatter<<<ge, B, 0, stream>>>(row, col, acc1, out, e);
    gcn_final  <<<gn, B, 0, stream>>>(deg_dinv, acc1, b2, out, n);
}

// Round 4
// 750.333 us; speedup vs baseline: 3.2967x; 3.2967x over previous
//
#include <hip/hip_runtime.h>

// GCN, 2 layers, in-dim 1, scalar-per-node propagation (formula verified R3):
//   deg[c] = 1 + indeg(c); dinv = rsqrt(deg)
//   S[c]   = dinv[c] * ( xd[c] + sum_{(r,c)} xd[r] ),  xd = dinv*x
//   td[r]  = dinv[r] * sum_f relu(b1[f] + W1[f]*S[r]) * W2[f]
//   y[c]   = clip( b2 + dinv[c] * ( td[c] + sum_{(r,c)} td[r] ), -0.5, 9.5 )
//
// R3 counters: 48M global fp atomics @ 20.6 G/s, 500 MB HBM WRITE per scatter
// (32 B/atomic write-through at the coherence point) -> atomic-bound.
// Fix: counting-sort edges by col into buckets of SZ=2048 nodes; one block
// owns each bucket and accumulates in LDS (ds_add_f32), flushing with plain
// stores. One sort serves deg + both scatters; mid/final fused into flushes.

#define SZ      2048
#define BSHIFT  11
#define BMASK   2047u
#define ROWBITS 21
#define ROWMASK ((1u << ROWBITS) - 1u)
#define NBMAX   512

// ---------------- sorted path ----------------

__global__ void gcn_zero(unsigned* __restrict__ tot, int nb) {
    for (int i = threadIdx.x; i < nb; i += blockDim.x) tot[i] = 0u;
}

__global__ void gcn_hist(const int* __restrict__ col, unsigned* __restrict__ tot,
                         int e, int nb) {
    __shared__ unsigned h[NBMAX];
    for (int i = threadIdx.x; i < nb; i += blockDim.x) h[i] = 0u;
    __syncthreads();
    int stride = gridDim.x * blockDim.x;
    for (int i = blockIdx.x * blockDim.x + threadIdx.x; i < e; i += stride)
        atomicAdd(&h[((unsigned)col[i]) >> BSHIFT], 1u);
    __syncthreads();
    for (int i = threadIdx.x; i < nb; i += blockDim.x)
        if (h[i]) atomicAdd(&tot[i], h[i]);
}

__global__ void gcn_scan(const unsigned* __restrict__ tot, unsigned* __restrict__ start,
                         unsigned* __restrict__ cursor, int nb) {
    __shared__ unsigned s[NBMAX];
    int tid = threadIdx.x;
    unsigned v = (tid < nb) ? tot[tid] : 0u;
    s[tid] = v;
    __syncthreads();
    for (int off = 1; off < NBMAX; off <<= 1) {
        unsigned t = (tid >= off) ? s[tid - off] : 0u;
        __syncthreads();
        s[tid] += t;
        __syncthreads();
    }
    if (tid < nb) { unsigned ex = s[tid] - v; start[tid] = ex; cursor[tid] = ex; }
    if (tid == NBMAX - 1) start[nb] = s[NBMAX - 1];
}

__global__ void gcn_reorder(const int* __restrict__ row, const int* __restrict__ col,
                            unsigned* __restrict__ cursor, unsigned* __restrict__ sorted,
                            int e, int nb) {
    __shared__ unsigned h[NBMAX];
    __shared__ unsigned base[NBMAX];
    int chunk = (e + gridDim.x - 1) / gridDim.x;
    int lo = blockIdx.x * chunk;
    int hi = min(e, lo + chunk);
    for (int i = threadIdx.x; i < nb; i += blockDim.x) h[i] = 0u;
    __syncthreads();
    for (int i = lo + threadIdx.x; i < hi; i += blockDim.x)
        atomicAdd(&h[((unsigned)col[i]) >> BSHIFT], 1u);
    __syncthreads();
    for (int i = threadIdx.x; i < nb; i += blockDim.x) {
        unsigned c = h[i];
        base[i] = c ? atomicAdd(&cursor[i], c) : 0u;
    }
    __syncthreads();
    for (int i = threadIdx.x; i < nb; i += blockDim.x) h[i] = 0u;
    __syncthreads();
    for (int i = lo + threadIdx.x; i < hi; i += blockDim.x) {
        unsigned c = (unsigned)col[i];
        unsigned b = c >> BSHIFT;
        unsigned off = atomicAdd(&h[b], 1u);
        sorted[base[b] + off] = ((c & BMASK) << ROWBITS) | (unsigned)row[i];
    }
}

// deg -> dinv, xd. One block per bucket (exclusive node range, plain stores).
__global__ void gcn_degx(const unsigned* __restrict__ sorted, const unsigned* __restrict__ start,
                         const float* __restrict__ x, float* __restrict__ dinv,
                         float* __restrict__ xd, int n) {
    __shared__ float acc[SZ];
    for (int i = threadIdx.x; i < SZ; i += blockDim.x) acc[i] = 0.0f;
    __syncthreads();
    int lo = start[blockIdx.x], hi = start[blockIdx.x + 1];
    for (int i = lo + threadIdx.x; i < hi; i += blockDim.x)
        atomicAdd(&acc[sorted[i] >> ROWBITS], 1.0f);
    __syncthreads();
    int nbase = blockIdx.x * SZ;
    for (int i = threadIdx.x; i < SZ; i += blockDim.x) {
        int node = nbase + i;
        if (node < n) {
            float d = rsqrtf(1.0f + acc[i]);
            dinv[node] = d;
            xd[node] = d * x[node];
        }
    }
}

// layer-1 scatter + fused pointwise MLP -> td
__global__ void gcn_pass1(const unsigned* __restrict__ sorted, const unsigned* __restrict__ start,
                          const float* __restrict__ dinv, const float* __restrict__ xd,
                          float* __restrict__ td,
                          const float* __restrict__ W1, const float* __restrict__ b1,
                          const float* __restrict__ W2, int n) {
    __shared__ float acc[SZ];
    __shared__ float w1[10], bb1[10], w2[10];
    if (threadIdx.x < 10) {
        w1[threadIdx.x] = W1[threadIdx.x];
        bb1[threadIdx.x] = b1[threadIdx.x];
        w2[threadIdx.x] = W2[threadIdx.x];
    }
    for (int i = threadIdx.x; i < SZ; i += blockDim.x) acc[i] = 0.0f;
    __syncthreads();
    int lo = start[blockIdx.x], hi = start[blockIdx.x + 1];
    for (int i = lo + threadIdx.x; i < hi; i += blockDim.x) {
        unsigned p = sorted[i];
        atomicAdd(&acc[p >> ROWBITS], xd[p & ROWMASK]);
    }
    __syncthreads();
    int nbase = blockIdx.x * SZ;
    for (int i = threadIdx.x; i < SZ; i += blockDim.x) {
        int node = nbase + i;
        if (node < n) {
            float d = dinv[node];
            float S = d * (acc[i] + xd[node]);
            float t = 0.0f;
            #pragma unroll
            for (int f = 0; f < 10; ++f) {
                float h = fmaf(w1[f], S, bb1[f]);
                h = h > 0.0f ? h : 0.0f;
                t = fmaf(h, w2[f], t);
            }
            td[node] = d * t;
        }
    }
}

// layer-2 scatter + fused bias/clip -> out
__global__ void gcn_pass2(const unsigned* __restrict__ sorted, const unsigned* __restrict__ start,
                          const float* __restrict__ dinv, const float* __restrict__ td,
                          const float* __restrict__ b2, float* __restrict__ out, int n) {
    __shared__ float acc[SZ];
    for (int i = threadIdx.x; i < SZ; i += blockDim.x) acc[i] = 0.0f;
    __syncthreads();
    int lo = start[blockIdx.x], hi = start[blockIdx.x + 1];
    for (int i = lo + threadIdx.x; i < hi; i += blockDim.x) {
        unsigned p = sorted[i];
        atomicAdd(&acc[p >> ROWBITS], td[p & ROWMASK]);
    }
    __syncthreads();
    int nbase = blockIdx.x * SZ;
    float bias = b2[0];
    for (int i = threadIdx.x; i < SZ; i += blockDim.x) {
        int node = nbase + i;
        if (node < n) {
            float y = bias + dinv[node] * (acc[i] + td[node]);
            out[node] = fminf(fmaxf(y, -0.5f), 9.5f);
        }
    }
}

// ---------------- fallback path (R3, passing) ----------------

__global__ void gcn_init(float* __restrict__ deg, float* __restrict__ acc1,
                         float* __restrict__ acc2, int n) {
    int i = blockIdx.x * blockDim.x + threadIdx.x;
    if (i < n) { deg[i] = 1.0f; acc1[i] = 0.0f; acc2[i] = 0.0f; }
}
__global__ void gcn_deg(const int* __restrict__ col, float* __restrict__ deg, int e) {
    int i = blockIdx.x * blockDim.x + threadIdx.x;
    if (i < e) atomicAdd(&deg[col[i]], 1.0f);
}
__global__ void gcn_dinv(const float* __restrict__ x, float* __restrict__ deg_dinv,
                         float* __restrict__ xd, int n) {
    int i = blockIdx.x * blockDim.x + threadIdx.x;
    if (i < n) { float d = rsqrtf(deg_dinv[i]); deg_dinv[i] = d; xd[i] = d * x[i]; }
}
__global__ void gcn_scatter(const int* __restrict__ row, const int* __restrict__ col,
                            const float* __restrict__ v, float* __restrict__ acc, int e) {
    int i = blockIdx.x * blockDim.x + threadIdx.x;
    if (i < e) atomicAdd(&acc[col[i]], v[row[i]]);
}
__global__ void gcn_mid(const float* __restrict__ dinv, const float* __restrict__ xd,
                        float* __restrict__ acc1_td,
                        const float* __restrict__ W1, const float* __restrict__ b1,
                        const float* __restrict__ W2, int n) {
    int i = blockIdx.x * blockDim.x + threadIdx.x;
    if (i < n) {
        float d = dinv[i];
        float S = d * (acc1_td[i] + xd[i]);
        float t = 0.0f;
        #pragma unroll
        for (int f = 0; f < 10; ++f) {
            float h = fmaf(W1[f], S, b1[f]);
            h = h > 0.0f ? h : 0.0f;
            t = fmaf(h, W2[f], t);
        }
        acc1_td[i] = d * t;
    }
}
__global__ void gcn_final(const float* __restrict__ dinv, const float* __restrict__ td,
                          const float* __restrict__ b2, float* __restrict__ out_acc2, int n) {
    int i = blockIdx.x * blockDim.x + threadIdx.x;
    if (i < n) {
        float y = b2[0] + dinv[i] * (out_acc2[i] + td[i]);
        out_acc2[i] = fminf(fmaxf(y, -0.5f), 9.5f);
    }
}

extern "C" void kernel_launch(void* const* d_in, const int* in_sizes, int n_in,
                              void* d_out, int out_size, void* d_ws, size_t ws_size,
                              hipStream_t stream) {
    const float* x  = (const float*)d_in[0];
    const int*   ei = (const int*)d_in[1];     // int32 per harness convention
    const float* W1 = (const float*)d_in[2];
    const float* b1 = (const float*)d_in[3];
    const float* W2 = (const float*)d_in[4];
    const float* b2 = (const float*)d_in[5];

    const int n = in_sizes[0];
    const int e = in_sizes[1] / 2;
    const int* row = ei;
    const int* col = ei + e;
    float* out = (float*)d_out;

    const int nb = (n + SZ - 1) / SZ;

    // ws layout (sorted path):
    // sorted: e u32 | dinv: n f32 | xd: n f32 | td: n f32 |
    // tot: nb u32 | start: nb+1 u32 | cursor: nb u32
    size_t need = (size_t)e * 4 + (size_t)n * 12 + (size_t)(3 * nb + 1) * 4 + 256;

    if (ws_size >= need && nb <= NBMAX && (unsigned)n <= ROWMASK) {
        unsigned* sorted = (unsigned*)d_ws;
        float*    dinv   = (float*)(sorted + e);
        float*    xd     = dinv + n;
        float*    td     = xd + n;
        unsigned* tot    = (unsigned*)(td + n);
        unsigned* start  = tot + nb;
        unsigned* cursor = start + nb + 1;

        gcn_zero   <<<1,   512, 0, stream>>>(tot, nb);
        gcn_hist   <<<512, 256, 0, stream>>>(col, tot, e, nb);
        gcn_scan   <<<1, NBMAX, 0, stream>>>(tot, start, cursor, nb);
        gcn_reorder<<<512, 256, 0, stream>>>(row, col, cursor, sorted, e, nb);
        gcn_degx   <<<nb, 1024, 0, stream>>>(sorted, start, x, dinv, xd, n);
        gcn_pass1  <<<nb, 1024, 0, stream>>>(sorted, start, dinv, xd, td, W1, b1, W2, n);
        gcn_pass2  <<<nb, 1024, 0, stream>>>(sorted, start, dinv, td, b2, out, n);
    } else {
        // fallback: global-atomic path (R3, passing)
        float* deg_dinv = (float*)d_ws;
        float* xd       = deg_dinv + n;
        float* acc1     = deg_dinv + 2 * (size_t)n;
        const int B = 256;
        const int gn = (n + B - 1) / B;
        const int ge = (e + B - 1) / B;
        gcn_init   <<<gn, B, 0, stream>>>(deg_dinv, acc1, out, n);
        gcn_deg    <<<ge, B, 0, stream>>>(col, deg_dinv, e);
        gcn_dinv   <<<gn, B, 0, stream>>>(x, deg_dinv, xd, n);
        gcn_scatter<<<ge, B, 0, stream>>>(row, col, xd, acc1, e);
        gcn_mid    <<<gn, B, 0, stream>>>(deg_dinv, xd, acc1, W1, b1, W2, n);
        gcn_scatter<<<ge, B, 0, stream>>>(row, col, acc1, out, e);
        gcn_final  <<<gn, B, 0, stream>>>(deg_dinv, acc1, b2, out, n);
    }
}

// Round 5
// 554.460 us; speedup vs baseline: 4.4613x; 1.3533x over previous
//
#include <hip/hip_runtime.h>

// GCN, 2 layers, in-dim 1, scalar-per-node propagation (verified R3/R4):
//   deg[c] = 1 + indeg(c); dinv = rsqrt(deg)
//   S[c]   = dinv[c] * ( xd[c] + sum_{(r,c)} xd[r] ),  xd = dinv*x
//   td[r]  = dinv[r] * sum_f relu(b1[f] + W1[f]*S[r]) * W2[f]
//   y[c]   = clip( b2 + dinv[c] * ( td[c] + sum_{(r,c)} td[r] ), -0.5, 9.5 )
//
// R4 counters: gcn_reorder 265 us, WRITE 269 MB (4.2x amp, scattered u32
// stores), occupancy 22% (grid 512 = 8/32 waves). Fix: deterministic
// radix-partition: per-chunk histogram -> global scan of H[chunk][bucket]
// (exact offsets, no atomics) -> local bucket-sort in LDS -> contiguous
// per-bucket runs written coalesced.

#define SZ      2048
#define BSHIFT  11
#define BMASK   2047u
#define ROWBITS 21
#define ROWMASK ((1u << ROWBITS) - 1u)
#define CHUNK   8192

// ---------- phase 1: per-chunk histogram ----------
__global__ __launch_bounds__(256) void gcn_hist(const int* __restrict__ col,
                                                unsigned* __restrict__ H, int e) {
    __shared__ unsigned h[256];
    int c = blockIdx.x;
    int lo = c * CHUNK, hi = min(e, lo + CHUNK);
    h[threadIdx.x] = 0u;
    __syncthreads();
    for (int i = lo + threadIdx.x; i < hi; i += 256)
        atomicAdd(&h[((unsigned)col[i]) >> BSHIFT], 1u);
    __syncthreads();
    H[(size_t)c * 256 + threadIdx.x] = h[threadIdx.x];
}

// ---------- phase 2a: per-bucket scan over chunks (H -> exclusive offsets, T = totals) ----------
__global__ __launch_bounds__(256) void gcn_scan1(unsigned* __restrict__ H,
                                                 unsigned* __restrict__ T, int C) {
    int b = blockIdx.x, tid = threadIdx.x;
    int L = (C + 255) / 256;
    int c0 = tid * L;
    unsigned partial = 0;
    for (int k = 0; k < L; ++k) {
        int c = c0 + k;
        if (c < C) partial += H[(size_t)c * 256 + b];
    }
    __shared__ unsigned s[256];
    s[tid] = partial;
    __syncthreads();
    for (int off = 1; off < 256; off <<= 1) {
        unsigned t = (tid >= off) ? s[tid - off] : 0u;
        __syncthreads();
        s[tid] += t;
        __syncthreads();
    }
    unsigned run = s[tid] - partial;           // exclusive prefix
    for (int k = 0; k < L; ++k) {
        int c = c0 + k;
        if (c < C) {
            unsigned tmp = H[(size_t)c * 256 + b];
            H[(size_t)c * 256 + b] = run;
            run += tmp;
        }
    }
    if (tid == 255) T[b] = s[255];
}

// ---------- phase 2b: bucket-level exclusive scan ----------
__global__ __launch_bounds__(256) void gcn_scan2(const unsigned* __restrict__ T,
                                                 unsigned* __restrict__ S) {
    int tid = threadIdx.x;
    __shared__ unsigned s[256];
    unsigned v = T[tid];
    s[tid] = v;
    __syncthreads();
    for (int off = 1; off < 256; off <<= 1) {
        unsigned t = (tid >= off) ? s[tid - off] : 0u;
        __syncthreads();
        s[tid] += t;
        __syncthreads();
    }
    S[tid] = s[tid] - v;
}

// ---------- phase 3: local bucket-sort + coalesced write ----------
__global__ __launch_bounds__(512) void gcn_reorder(const int* __restrict__ row,
                                                   const int* __restrict__ col,
                                                   const unsigned* __restrict__ H,   // offsets
                                                   const unsigned* __restrict__ S,
                                                   unsigned* __restrict__ sorted, int e) {
    __shared__ unsigned keys[CHUNK];
    __shared__ unsigned char bOf[CHUNK];
    __shared__ unsigned hist[256], scanL[256], cnt[256], baseG[256];
    int c = blockIdx.x, tid = threadIdx.x;
    int lo = c * CHUNK, hi = min(e, lo + CHUNK);
    if (tid < 256) { hist[tid] = 0u; cnt[tid] = 0u; }
    __syncthreads();
    for (int i = lo + tid; i < hi; i += 512)
        atomicAdd(&hist[((unsigned)col[i]) >> BSHIFT], 1u);
    __syncthreads();
    if (tid < 256) scanL[tid] = hist[tid];
    __syncthreads();
    for (int off = 1; off < 256; off <<= 1) {
        unsigned t = 0u;
        if (tid < 256 && tid >= off) t = scanL[tid - off];
        __syncthreads();
        if (tid < 256) scanL[tid] += t;
        __syncthreads();
    }
    if (tid < 256) scanL[tid] -= hist[tid];    // exclusive
    __syncthreads();
    for (int i = lo + tid; i < hi; i += 512) {
        unsigned cv = (unsigned)col[i];
        unsigned b = cv >> BSHIFT;
        unsigned r = scanL[b] + atomicAdd(&cnt[b], 1u);
        keys[r] = ((cv & BMASK) << ROWBITS) | (unsigned)row[i];
        bOf[r] = (unsigned char)b;
    }
    if (tid < 256) baseG[tid] = S[tid] + H[(size_t)c * 256 + tid] - scanL[tid];
    __syncthreads();
    int m = hi - lo;
    for (int j = tid; j < m; j += 512)
        sorted[baseG[bOf[j]] + j] = keys[j];
}

// ---------- consume passes (one block owns one bucket of SZ nodes) ----------
__global__ __launch_bounds__(1024) void gcn_degx(const unsigned* __restrict__ sorted,
                                                 const unsigned* __restrict__ S,
                                                 const float* __restrict__ x,
                                                 float* __restrict__ dinv,
                                                 float* __restrict__ xd, int n, int e) {
    __shared__ float acc[SZ];
    for (int i = threadIdx.x; i < SZ; i += blockDim.x) acc[i] = 0.0f;
    __syncthreads();
    int lo = S[blockIdx.x];
    int hi = (blockIdx.x + 1 < 256) ? (int)S[blockIdx.x + 1] : e;
    for (int i = lo + threadIdx.x; i < hi; i += blockDim.x)
        atomicAdd(&acc[sorted[i] >> ROWBITS], 1.0f);
    __syncthreads();
    int nbase = blockIdx.x * SZ;
    for (int i = threadIdx.x; i < SZ; i += blockDim.x) {
        int node = nbase + i;
        if (node < n) {
            float d = rsqrtf(1.0f + acc[i]);
            dinv[node] = d;
            xd[node] = d * x[node];
        }
    }
}

__global__ __launch_bounds__(1024) void gcn_pass1(const unsigned* __restrict__ sorted,
                                                  const unsigned* __restrict__ S,
                                                  const float* __restrict__ dinv,
                                                  const float* __restrict__ xd,
                                                  float* __restrict__ td,
                                                  const float* __restrict__ W1,
                                                  const float* __restrict__ b1,
                                                  const float* __restrict__ W2, int n, int e) {
    __shared__ float acc[SZ];
    __shared__ float w1[10], bb1[10], w2[10];
    if (threadIdx.x < 10) {
        w1[threadIdx.x] = W1[threadIdx.x];
        bb1[threadIdx.x] = b1[threadIdx.x];
        w2[threadIdx.x] = W2[threadIdx.x];
    }
    for (int i = threadIdx.x; i < SZ; i += blockDim.x) acc[i] = 0.0f;
    __syncthreads();
    int lo = S[blockIdx.x];
    int hi = (blockIdx.x + 1 < 256) ? (int)S[blockIdx.x + 1] : e;
    for (int i = lo + threadIdx.x; i < hi; i += blockDim.x) {
        unsigned p = sorted[i];
        atomicAdd(&acc[p >> ROWBITS], xd[p & ROWMASK]);
    }
    __syncthreads();
    int nbase = blockIdx.x * SZ;
    for (int i = threadIdx.x; i < SZ; i += blockDim.x) {
        int node = nbase + i;
        if (node < n) {
            float d = dinv[node];
            float Sv = d * (acc[i] + xd[node]);
            float t = 0.0f;
            #pragma unroll
            for (int f = 0; f < 10; ++f) {
                float h = fmaf(w1[f], Sv, bb1[f]);
                h = h > 0.0f ? h : 0.0f;
                t = fmaf(h, w2[f], t);
            }
            td[node] = d * t;
        }
    }
}

__global__ __launch_bounds__(1024) void gcn_pass2(const unsigned* __restrict__ sorted,
                                                  const unsigned* __restrict__ S,
                                                  const float* __restrict__ dinv,
                                                  const float* __restrict__ td,
                                                  const float* __restrict__ b2,
                                                  float* __restrict__ out, int n, int e) {
    __shared__ float acc[SZ];
    for (int i = threadIdx.x; i < SZ; i += blockDim.x) acc[i] = 0.0f;
    __syncthreads();
    int lo = S[blockIdx.x];
    int hi = (blockIdx.x + 1 < 256) ? (int)S[blockIdx.x + 1] : e;
    for (int i = lo + threadIdx.x; i < hi; i += blockDim.x) {
        unsigned p = sorted[i];
        atomicAdd(&acc[p >> ROWBITS], td[p & ROWMASK]);
    }
    __syncthreads();
    int nbase = blockIdx.x * SZ;
    float bias = b2[0];
    for (int i = threadIdx.x; i < SZ; i += blockDim.x) {
        int node = nbase + i;
        if (node < n) {
            float y = bias + dinv[node] * (acc[i] + td[node]);
            out[node] = fminf(fmaxf(y, -0.5f), 9.5f);
        }
    }
}

// ---------------- fallback path (R3, passing) ----------------
__global__ void gcn_init(float* deg, float* acc1, float* acc2, int n) {
    int i = blockIdx.x * blockDim.x + threadIdx.x;
    if (i < n) { deg[i] = 1.0f; acc1[i] = 0.0f; acc2[i] = 0.0f; }
}
__global__ void gcn_deg(const int* col, float* deg, int e) {
    int i = blockIdx.x * blockDim.x + threadIdx.x;
    if (i < e) atomicAdd(&deg[col[i]], 1.0f);
}
__global__ void gcn_dinv(const float* x, float* deg_dinv, float* xd, int n) {
    int i = blockIdx.x * blockDim.x + threadIdx.x;
    if (i < n) { float d = rsqrtf(deg_dinv[i]); deg_dinv[i] = d; xd[i] = d * x[i]; }
}
__global__ void gcn_scatter(const int* row, const int* col, const float* v, float* acc, int e) {
    int i = blockIdx.x * blockDim.x + threadIdx.x;
    if (i < e) atomicAdd(&acc[col[i]], v[row[i]]);
}
__global__ void gcn_mid(const float* dinv, const float* xd, float* acc1_td,
                        const float* W1, const float* b1, const float* W2, int n) {
    int i = blockIdx.x * blockDim.x + threadIdx.x;
    if (i < n) {
        float d = dinv[i];
        float Sv = d * (acc1_td[i] + xd[i]);
        float t = 0.0f;
        #pragma unroll
        for (int f = 0; f < 10; ++f) {
            float h = fmaf(W1[f], Sv, b1[f]);
            h = h > 0.0f ? h : 0.0f;
            t = fmaf(h, W2[f], t);
        }
        acc1_td[i] = d * t;
    }
}
__global__ void gcn_final(const float* dinv, const float* td, const float* b2,
                          float* out_acc2, int n) {
    int i = blockIdx.x * blockDim.x + threadIdx.x;
    if (i < n) {
        float y = b2[0] + dinv[i] * (out_acc2[i] + td[i]);
        out_acc2[i] = fminf(fmaxf(y, -0.5f), 9.5f);
    }
}

extern "C" void kernel_launch(void* const* d_in, const int* in_sizes, int n_in,
                              void* d_out, int out_size, void* d_ws, size_t ws_size,
                              hipStream_t stream) {
    const float* x  = (const float*)d_in[0];
    const int*   ei = (const int*)d_in[1];     // int32 per harness convention
    const float* W1 = (const float*)d_in[2];
    const float* b1 = (const float*)d_in[3];
    const float* W2 = (const float*)d_in[4];
    const float* b2 = (const float*)d_in[5];

    const int n = in_sizes[0];
    const int e = in_sizes[1] / 2;
    const int* row = ei;
    const int* col = ei + e;
    float* out = (float*)d_out;

    const int nb = (n + SZ - 1) / SZ;           // buckets (245)
    const int C  = (e + CHUNK - 1) / CHUNK;     // chunks (1954)

    // ws: sorted u32[e] | dinv f32[n] | xd f32[n] | region: max(td f32[n], H u32[C*256]) | T[256] S[256]
    size_t regionB = (size_t)4 * n;
    size_t hB = (size_t)1024 * C;
    if (hB > regionB) regionB = hB;
    size_t need = (size_t)4 * e + (size_t)8 * n + regionB + 4096;

    if (ws_size >= need && nb <= 256 && (unsigned)n <= ROWMASK) {
        unsigned* sorted = (unsigned*)d_ws;
        float*    dinv   = (float*)(sorted + e);
        float*    xd     = dinv + n;
        char*     region = (char*)(xd + n);
        float*    td     = (float*)region;
        unsigned* H      = (unsigned*)region;   // lifetime disjoint from td
        unsigned* T      = (unsigned*)(region + regionB);
        unsigned* S      = T + 256;

        gcn_hist   <<<C,   256, 0, stream>>>(col, H, e);
        gcn_scan1  <<<256, 256, 0, stream>>>(H, T, C);
        gcn_scan2  <<<1,   256, 0, stream>>>(T, S);
        gcn_reorder<<<C,   512, 0, stream>>>(row, col, H, S, sorted, e);
        gcn_degx   <<<nb, 1024, 0, stream>>>(sorted, S, x, dinv, xd, n, e);
        gcn_pass1  <<<nb, 1024, 0, stream>>>(sorted, S, dinv, xd, td, W1, b1, W2, n, e);
        gcn_pass2  <<<nb, 1024, 0, stream>>>(sorted, S, dinv, td, b2, out, n, e);
    } else {
        float* deg_dinv = (float*)d_ws;
        float* xd       = deg_dinv + n;
        float* acc1     = deg_dinv + 2 * (size_t)n;
        const int B = 256;
        const int gn = (n + B - 1) / B;
        const int ge = (e + B - 1) / B;
        gcn_init   <<<gn, B, 0, stream>>>(deg_dinv, acc1, out, n);
        gcn_deg    <<<ge, B, 0, stream>>>(col, deg_dinv, e);
        gcn_dinv   <<<gn, B, 0, stream>>>(x, deg_dinv, xd, n);
        gcn_scatter<<<ge, B, 0, stream>>>(row, col, xd, acc1, e);
        gcn_mid    <<<gn, B, 0, stream>>>(deg_dinv, xd, acc1, W1, b1, W2, n);
        gcn_scatter<<<ge, B, 0, stream>>>(row, col, acc1, out, e);
        gcn_final  <<<gn, B, 0, stream>>>(deg_dinv, acc1, b2, out, n);
    }
}

// Round 6
// 540.664 us; speedup vs baseline: 4.5751x; 1.0255x over previous
//
#include <hip/hip_runtime.h>

// GCN, 2 layers, in-dim 1, scalar-per-node propagation (verified R3-R5):
//   deg[c] = 1 + indeg(c); dinv = rsqrt(deg)
//   S[c]   = dinv[c] * ( xd[c] + sum_{(r,c)} xd[r] ),  xd = dinv*x
//   td[r]  = dinv[r] * sum_f relu(b1[f] + W1[f]*S[r]) * W2[f]
//   y[c]   = clip( b2 + dinv[c] * ( td[c] + sum_{(r,c)} td[r] ), -0.5, 9.5 )
//
// R5: reorder 101us @ 50% occ, 6.1M LDS bank conflicts (bOf byte array);
// consume passes 1 block/bucket = 50% occ. This round: (1) reorder drops
// bOf via binary search over scanL (LDS 45->36KB, 4 blocks/CU);
// (2) consume passes split 2 blocks/bucket -> private partials P[2][.],
// node-parallel combine kernels; uint4 sorted reads. (3) int4 hist.

#define SZ      2048
#define BSHIFT  11
#define BMASK   2047u
#define ROWBITS 21
#define ROWMASK ((1u << ROWBITS) - 1u)
#define CHUNK   8192

// ---------- phase 1: per-chunk histogram (int4) ----------
__global__ __launch_bounds__(256) void gcn_hist(const int* __restrict__ col,
                                                unsigned* __restrict__ H, int e) {
    __shared__ unsigned h[256];
    int c = blockIdx.x, tid = threadIdx.x;
    int lo = c * CHUNK, hi = min(e, lo + CHUNK);
    h[tid] = 0u;
    __syncthreads();
    int nv = (hi - lo) >> 2;
    const int4* cv = (const int4*)(col + lo);
    for (int k = tid; k < nv; k += 256) {
        int4 v = cv[k];
        atomicAdd(&h[((unsigned)v.x) >> BSHIFT], 1u);
        atomicAdd(&h[((unsigned)v.y) >> BSHIFT], 1u);
        atomicAdd(&h[((unsigned)v.z) >> BSHIFT], 1u);
        atomicAdd(&h[((unsigned)v.w) >> BSHIFT], 1u);
    }
    for (int i = lo + (nv << 2) + tid; i < hi; i += 256)
        atomicAdd(&h[((unsigned)col[i]) >> BSHIFT], 1u);
    __syncthreads();
    H[(size_t)c * 256 + tid] = h[tid];
}

// ---------- phase 2a: per-bucket scan over chunks (H -> exclusive offsets, T totals) ----------
__global__ __launch_bounds__(256) void gcn_scan1(unsigned* __restrict__ H,
                                                 unsigned* __restrict__ T, int C) {
    int b = blockIdx.x, tid = threadIdx.x;
    int L = (C + 255) / 256;
    int c0 = tid * L;
    unsigned partial = 0;
    for (int k = 0; k < L; ++k) {
        int c = c0 + k;
        if (c < C) partial += H[(size_t)c * 256 + b];
    }
    __shared__ unsigned s[256];
    s[tid] = partial;
    __syncthreads();
    for (int off = 1; off < 256; off <<= 1) {
        unsigned t = (tid >= off) ? s[tid - off] : 0u;
        __syncthreads();
        s[tid] += t;
        __syncthreads();
    }
    unsigned run = s[tid] - partial;
    for (int k = 0; k < L; ++k) {
        int c = c0 + k;
        if (c < C) {
            unsigned tmp = H[(size_t)c * 256 + b];
            H[(size_t)c * 256 + b] = run;
            run += tmp;
        }
    }
    if (tid == 255) T[b] = s[255];
}

// ---------- phase 2b: bucket-level exclusive scan ----------
__global__ __launch_bounds__(256) void gcn_scan2(const unsigned* __restrict__ T,
                                                 unsigned* __restrict__ S) {
    int tid = threadIdx.x;
    __shared__ unsigned s[256];
    unsigned v = T[tid];
    s[tid] = v;
    __syncthreads();
    for (int off = 1; off < 256; off <<= 1) {
        unsigned t = (tid >= off) ? s[tid - off] : 0u;
        __syncthreads();
        s[tid] += t;
        __syncthreads();
    }
    S[tid] = s[tid] - v;
}

// ---------- phase 3: local bucket-sort + coalesced write (binary search, no bOf) ----------
__global__ __launch_bounds__(512) void gcn_reorder(const int* __restrict__ row,
                                                   const int* __restrict__ col,
                                                   const unsigned* __restrict__ H,
                                                   const unsigned* __restrict__ S,
                                                   unsigned* __restrict__ sorted, int e) {
    __shared__ unsigned keys[CHUNK];
    __shared__ unsigned hist[256], scanL[256], cnt[256], baseG[256];
    int c = blockIdx.x, tid = threadIdx.x;
    int lo = c * CHUNK, hi = min(e, lo + CHUNK), m = hi - lo;
    if (tid < 256) { hist[tid] = 0u; cnt[tid] = 0u; }
    __syncthreads();
    for (int i = lo + tid; i < hi; i += 512)
        atomicAdd(&hist[((unsigned)col[i]) >> BSHIFT], 1u);
    __syncthreads();
    if (tid < 256) scanL[tid] = hist[tid];
    __syncthreads();
    for (int off = 1; off < 256; off <<= 1) {
        unsigned t = 0u;
        if (tid < 256 && tid >= off) t = scanL[tid - off];
        __syncthreads();
        if (tid < 256) scanL[tid] += t;
        __syncthreads();
    }
    if (tid < 256) scanL[tid] -= hist[tid];    // exclusive
    __syncthreads();
    for (int i = lo + tid; i < hi; i += 512) {
        unsigned cv = (unsigned)col[i];
        unsigned b = cv >> BSHIFT;
        unsigned r = scanL[b] + atomicAdd(&cnt[b], 1u);
        keys[r] = ((cv & BMASK) << ROWBITS) | (unsigned)row[i];
    }
    if (tid < 256) baseG[tid] = S[tid] + H[(size_t)c * 256 + tid] - scanL[tid];
    __syncthreads();
    for (int j = tid; j < m; j += 512) {
        // largest b in [0,255] with scanL[b] <= j  (ranks are bucket-contiguous)
        int lo2 = 0, hi2 = 255;
        #pragma unroll
        for (int it = 0; it < 8; ++it) {
            int mid = (lo2 + hi2 + 1) >> 1;
            if (scanL[mid] <= (unsigned)j) lo2 = mid; else hi2 = mid - 1;
        }
        sorted[baseG[lo2] + j] = keys[j];
    }
}

// ---------- consume: 2 blocks per bucket -> private partials (coalesced flush) ----------
__global__ __launch_bounds__(1024) void gcn_count(const unsigned* __restrict__ sorted,
                                                  const unsigned* __restrict__ S,
                                                  float* __restrict__ P, int npad, int e) {
    __shared__ float acc[SZ];
    int b = blockIdx.x >> 1, g = blockIdx.x & 1, tid = threadIdx.x;
    for (int i = tid; i < SZ; i += 1024) acc[i] = 0.0f;
    __syncthreads();
    int lo = S[b];
    int hi = (b + 1 < 256) ? (int)S[b + 1] : e;
    int half = (hi - lo + 1) >> 1;
    int mylo = lo + g * half, myhi = min(hi, mylo + half);
    int i0 = min((mylo + 3) & ~3, myhi);
    for (int i = mylo + tid; i < i0; i += 1024)
        atomicAdd(&acc[sorted[i] >> ROWBITS], 1.0f);
    int nv = (myhi - i0) >> 2;
    const uint4* sv = (const uint4*)(sorted + i0);
    for (int k = tid; k < nv; k += 1024) {
        uint4 v = sv[k];
        atomicAdd(&acc[v.x >> ROWBITS], 1.0f);
        atomicAdd(&acc[v.y >> ROWBITS], 1.0f);
        atomicAdd(&acc[v.z >> ROWBITS], 1.0f);
        atomicAdd(&acc[v.w >> ROWBITS], 1.0f);
    }
    for (int i = i0 + (nv << 2) + tid; i < myhi; i += 1024)
        atomicAdd(&acc[sorted[i] >> ROWBITS], 1.0f);
    __syncthreads();
    size_t off = (size_t)g * npad + (size_t)b * SZ;
    for (int i = tid; i < SZ; i += 1024) P[off + i] = acc[i];
}

__global__ __launch_bounds__(1024) void gcn_gather(const unsigned* __restrict__ sorted,
                                                   const unsigned* __restrict__ S,
                                                   const float* __restrict__ src,
                                                   float* __restrict__ P, int npad, int e) {
    __shared__ float acc[SZ];
    int b = blockIdx.x >> 1, g = blockIdx.x & 1, tid = threadIdx.x;
    for (int i = tid; i < SZ; i += 1024) acc[i] = 0.0f;
    __syncthreads();
    int lo = S[b];
    int hi = (b + 1 < 256) ? (int)S[b + 1] : e;
    int half = (hi - lo + 1) >> 1;
    int mylo = lo + g * half, myhi = min(hi, mylo + half);
    int i0 = min((mylo + 3) & ~3, myhi);
    for (int i = mylo + tid; i < i0; i += 1024) {
        unsigned p = sorted[i];
        atomicAdd(&acc[p >> ROWBITS], src[p & ROWMASK]);
    }
    int nv = (myhi - i0) >> 2;
    const uint4* sv = (const uint4*)(sorted + i0);
    for (int k = tid; k < nv; k += 1024) {
        uint4 v = sv[k];
        float a = src[v.x & ROWMASK];
        float bb = src[v.y & ROWMASK];
        float cc = src[v.z & ROWMASK];
        float dd = src[v.w & ROWMASK];
        atomicAdd(&acc[v.x >> ROWBITS], a);
        atomicAdd(&acc[v.y >> ROWBITS], bb);
        atomicAdd(&acc[v.z >> ROWBITS], cc);
        atomicAdd(&acc[v.w >> ROWBITS], dd);
    }
    for (int i = i0 + (nv << 2) + tid; i < myhi; i += 1024) {
        unsigned p = sorted[i];
        atomicAdd(&acc[p >> ROWBITS], src[p & ROWMASK]);
    }
    __syncthreads();
    size_t off = (size_t)g * npad + (size_t)b * SZ;
    for (int i = tid; i < SZ; i += 1024) P[off + i] = acc[i];
}

// ---------- node-parallel combines ----------
__global__ __launch_bounds__(256) void gcn_comb0(const float* __restrict__ P, int npad,
                                                 const float* __restrict__ x,
                                                 float* __restrict__ dinv,
                                                 float* __restrict__ xd, int n) {
    int i = blockIdx.x * 256 + threadIdx.x;
    if (i < n) {
        float d = rsqrtf(1.0f + P[i] + P[(size_t)npad + i]);
        dinv[i] = d;
        xd[i] = d * x[i];
    }
}

__global__ __launch_bounds__(256) void gcn_comb1(const float* __restrict__ P, int npad,
                                                 const float* __restrict__ dinv,
                                                 float* __restrict__ xd,   // in: xd, out: td
                                                 const float* __restrict__ W1,
                                                 const float* __restrict__ b1,
                                                 const float* __restrict__ W2, int n) {
    int i = blockIdx.x * 256 + threadIdx.x;
    if (i < n) {
        float d = dinv[i];
        float Sv = d * (P[i] + P[(size_t)npad + i] + xd[i]);
        float t = 0.0f;
        #pragma unroll
        for (int f = 0; f < 10; ++f) {
            float h = fmaf(W1[f], Sv, b1[f]);
            h = h > 0.0f ? h : 0.0f;
            t = fmaf(h, W2[f], t);
        }
        xd[i] = d * t;
    }
}

__global__ __launch_bounds__(256) void gcn_comb2(const float* __restrict__ P, int npad,
                                                 const float* __restrict__ dinv,
                                                 const float* __restrict__ td,
                                                 const float* __restrict__ b2,
                                                 float* __restrict__ out, int n) {
    int i = blockIdx.x * 256 + threadIdx.x;
    if (i < n) {
        float y = b2[0] + dinv[i] * (P[i] + P[(size_t)npad + i] + td[i]);
        out[i] = fminf(fmaxf(y, -0.5f), 9.5f);
    }
}

// ---------------- fallback path (R3, passing) ----------------
__global__ void gcn_init(float* deg, float* acc1, float* acc2, int n) {
    int i = blockIdx.x * blockDim.x + threadIdx.x;
    if (i < n) { deg[i] = 1.0f; acc1[i] = 0.0f; acc2[i] = 0.0f; }
}
__global__ void gcn_deg(const int* col, float* deg, int e) {
    int i = blockIdx.x * blockDim.x + threadIdx.x;
    if (i < e) atomicAdd(&deg[col[i]], 1.0f);
}
__global__ void gcn_dinv(const float* x, float* deg_dinv, float* xd, int n) {
    int i = blockIdx.x * blockDim.x + threadIdx.x;
    if (i < n) { float d = rsqrtf(deg_dinv[i]); deg_dinv[i] = d; xd[i] = d * x[i]; }
}
__global__ void gcn_scatter(const int* row, const int* col, const float* v, float* acc, int e) {
    int i = blockIdx.x * blockDim.x + threadIdx.x;
    if (i < e) atomicAdd(&acc[col[i]], v[row[i]]);
}
__global__ void gcn_mid(const float* dinv, const float* xd, float* acc1_td,
                        const float* W1, const float* b1, const float* W2, int n) {
    int i = blockIdx.x * blockDim.x + threadIdx.x;
    if (i < n) {
        float d = dinv[i];
        float Sv = d * (acc1_td[i] + xd[i]);
        float t = 0.0f;
        #pragma unroll
        for (int f = 0; f < 10; ++f) {
            float h = fmaf(W1[f], Sv, b1[f]);
            h = h > 0.0f ? h : 0.0f;
            t = fmaf(h, W2[f], t);
        }
        acc1_td[i] = d * t;
    }
}
__global__ void gcn_final(const float* dinv, const float* td, const float* b2,
                          float* out_acc2, int n) {
    int i = blockIdx.x * blockDim.x + threadIdx.x;
    if (i < n) {
        float y = b2[0] + dinv[i] * (out_acc2[i] + td[i]);
        out_acc2[i] = fminf(fmaxf(y, -0.5f), 9.5f);
    }
}

extern "C" void kernel_launch(void* const* d_in, const int* in_sizes, int n_in,
                              void* d_out, int out_size, void* d_ws, size_t ws_size,
                              hipStream_t stream) {
    const float* x  = (const float*)d_in[0];
    const int*   ei = (const int*)d_in[1];     // int32 per harness convention
    const float* W1 = (const float*)d_in[2];
    const float* b1 = (const float*)d_in[3];
    const float* W2 = (const float*)d_in[4];
    const float* b2 = (const float*)d_in[5];

    const int n = in_sizes[0];
    const int e = in_sizes[1] / 2;
    const int* row = ei;
    const int* col = ei + e;
    float* out = (float*)d_out;

    const int nb = (n + SZ - 1) / SZ;           // buckets (245)
    const int C  = (e + CHUNK - 1) / CHUNK;     // chunks (1954)
    const int npad = nb * SZ;

    // ws: sorted u32[e] | dinv f32[n] | xd f32[n] | P f32[2*npad] (H aliases) | T[256] S[256]
    size_t need = (size_t)4 * e + (size_t)8 * n + (size_t)8 * npad + 4096;
    bool hFits = (size_t)C * 256 <= (size_t)2 * npad;

    if (ws_size >= need && nb <= 256 && (unsigned)n <= ROWMASK && hFits) {
        unsigned* sorted = (unsigned*)d_ws;
        float*    dinv   = (float*)(sorted + e);
        float*    xd     = dinv + n;
        float*    P      = xd + n;              // 2*npad floats
        unsigned* H      = (unsigned*)P;        // lifetime ends at reorder
        unsigned* T      = (unsigned*)(P + (size_t)2 * npad);
        unsigned* S      = T + 256;

        const int gn = (n + 255) / 256;

        gcn_hist   <<<C,      256, 0, stream>>>(col, H, e);
        gcn_scan1  <<<256,    256, 0, stream>>>(H, T, C);
        gcn_scan2  <<<1,      256, 0, stream>>>(T, S);
        gcn_reorder<<<C,      512, 0, stream>>>(row, col, H, S, sorted, e);
        gcn_count  <<<nb * 2, 1024, 0, stream>>>(sorted, S, P, npad, e);
        gcn_comb0  <<<gn,     256, 0, stream>>>(P, npad, x, dinv, xd, n);
        gcn_gather <<<nb * 2, 1024, 0, stream>>>(sorted, S, xd, P, npad, e);
        gcn_comb1  <<<gn,     256, 0, stream>>>(P, npad, dinv, xd, W1, b1, W2, n);
        gcn_gather <<<nb * 2, 1024, 0, stream>>>(sorted, S, xd, P, npad, e);
        gcn_comb2  <<<gn,     256, 0, stream>>>(P, npad, dinv, xd, b2, out, n);
    } else {
        float* deg_dinv = (float*)d_ws;
        float* xd       = deg_dinv + n;
        float* acc1     = deg_dinv + 2 * (size_t)n;
        const int B = 256;
        const int gn = (n + B - 1) / B;
        const int ge = (e + B - 1) / B;
        gcn_init   <<<gn, B, 0, stream>>>(deg_dinv, acc1, out, n);
        gcn_deg    <<<ge, B, 0, stream>>>(col, deg_dinv, e);
        gcn_dinv   <<<gn, B, 0, stream>>>(x, deg_dinv, xd, n);
        gcn_scatter<<<ge, B, 0, stream>>>(row, col, xd, acc1, e);
        gcn_mid    <<<gn, B, 0, stream>>>(deg_dinv, xd, acc1, W1, b1, W2, n);
        gcn_scatter<<<ge, B, 0, stream>>>(row, col, acc1, out, e);
        gcn_final  <<<gn, B, 0, stream>>>(deg_dinv, acc1, b2, out, n);
    }
}